// Round 11
// baseline (313.821 us; speedup 1.0000x reference)
//
#include <hip/hip_runtime.h>
#include <math.h>

#define B 32
#define NH 32
#define NKV 8
#define GRP 4
#define HD 128
#define DIM 4096
#define NQKV 6144   // (NH + 2*NKV) * HD
#define WIN 4096
#define KS 32       // split-K chunks for the skinny GEMMs
#define SPLIT 16    // attention sequence chunks
#define SCHUNK (WIN / SPLIT)   // 256 positions per chunk
#define NSUP (SCHUNK / 32)     // 8 super-iters: 4 waves x 8 positions = 32/iter

__device__ __forceinline__ float fast_exp2(float x) {
#if __has_builtin(__builtin_amdgcn_exp2f)
  return __builtin_amdgcn_exp2f(x);
#else
  return exp2f(x);
#endif
}

// ---------------------------------------------------------------------------
// Skinny GEMM (R4 known-good): part[kc][b][f] = sum_{k in kc} X[b][k]*W[k][f]
// Grid (N/256, KS), block 256. LDS-staged X, broadcast float4 reads.
// ---------------------------------------------------------------------------
__global__ __launch_bounds__(256)
void gemv32_partial(const float* __restrict__ X, const float* __restrict__ W,
                    float* __restrict__ part, int K, int N) {
  const int f  = blockIdx.x * 256 + threadIdx.x;
  const int kc = blockIdx.y;
  const int kchunk = K / KS;
  const int k0 = kc * kchunk;

  __shared__ float xs[128][36];

  float acc[B];
#pragma unroll
  for (int b = 0; b < B; ++b) acc[b] = 0.f;

  for (int kb = 0; kb < kchunk; kb += 128) {
    __syncthreads();
    for (int idx = threadIdx.x; idx < B * 128; idx += 256) {
      int bb = idx >> 7;
      int kk = idx & 127;
      xs[kk][bb] = X[(size_t)bb * K + (k0 + kb + kk)];
    }
    __syncthreads();

    const float* wp = W + (size_t)(k0 + kb) * N + f;
#pragma unroll 4
    for (int kk = 0; kk < 128; ++kk) {
      float w = wp[(size_t)kk * N];
      const float4* xr = (const float4*)&xs[kk][0];
#pragma unroll
      for (int b4 = 0; b4 < 8; ++b4) {
        float4 xv = xr[b4];
        acc[b4 * 4 + 0] += xv.x * w;
        acc[b4 * 4 + 1] += xv.y * w;
        acc[b4 * 4 + 2] += xv.z * w;
        acc[b4 * 4 + 3] += xv.w * w;
      }
    }
  }

  float* pp = part + (size_t)kc * B * N + f;
#pragma unroll
  for (int b = 0; b < B; ++b) pp[(size_t)b * N] = acc[b];
}

// ---------------------------------------------------------------------------
// Reduce split-K partials: out[idx] = sum_kc part[kc][idx]
// ---------------------------------------------------------------------------
__global__ __launch_bounds__(256)
void reduce_partials(const float* __restrict__ part, float* __restrict__ out,
                     int total) {
  int idx = blockIdx.x * 256 + threadIdx.x;
  if (idx >= total) return;
  float s = 0.f;
#pragma unroll
  for (int kc = 0; kc < KS; ++kc) s += part[(size_t)kc * total + idx];
  out[idx] = s;
}

// ---------------------------------------------------------------------------
// Rotary: per (b, head) vector v (128), out[e] = sum_d v[d] * rot[d][e]
// q heads scaled by rsqrt(128)*log2(e) (fixed-base-2 softmax); k unscaled.
// ---------------------------------------------------------------------------
__global__ __launch_bounds__(128)
void rotary_kernel(const float* __restrict__ xqkv, const float* __restrict__ rot,
                   float* __restrict__ qrot, float* __restrict__ krot) {
  const int b = blockIdx.x;
  const int h = blockIdx.y;   // 0..39
  const int e = threadIdx.x;  // 0..127

  __shared__ float vec[HD];
  vec[e] = xqkv[(size_t)b * NQKV + h * HD + e];
  __syncthreads();

  float s = 0.f;
#pragma unroll 8
  for (int d = 0; d < HD; ++d) s += vec[d] * rot[d * HD + e];

  const float QSCALE = 0.08838834764831845f * 1.4426950408889634f;
  if (h < NH) {
    qrot[((size_t)b * NH + h) * HD + e] = s * QSCALE;
  } else {
    krot[((size_t)b * NKV + (h - NH)) * HD + e] = s;
  }
}

// ---------------------------------------------------------------------------
// Flash-decode attention partial (fixed-base softmax). PHASE-GROUPED memory:
// R4 lane mapping (half-wave owns a position; lane holds dims l32*4..+3 for
// all 4 heads -> every load instruction = 1KB unique contiguous). Each wave
// processes 8 positions per super-iteration: 4 K-loads (4KB burst), 4 V-loads
// (4KB burst), then compute; next super-iter's loads prefetched during
// compute. This replaces the 512B K/V ping-pong that thrashed DRAM pages.
// Constant trip count, branch-free p<slice masking. Stale-cache loop +
// one-shot new-token correction. Grid (B*NKV, SPLIT), block 256.
// ---------------------------------------------------------------------------
__global__ __launch_bounds__(256, 4)
void attn_partial(const float* __restrict__ cache_k, const float* __restrict__ cache_v,
                  const float* __restrict__ qrot, const float* __restrict__ krot,
                  const float* __restrict__ xqkv, const int* __restrict__ start_pos,
                  float* __restrict__ o_part, float* __restrict__ l_part) {
  const int pair = blockIdx.x;            // b * NKV + kvh
  const int b    = pair >> 3;
  const int kvh  = pair & 7;
  const int chunk = blockIdx.y;

  const int sp    = start_pos[0];
  const int cur   = sp & (WIN - 1);
  const int slice = (sp + 1 < WIN) ? (sp + 1) : WIN;

  const int tid  = threadIdx.x;
  const int wave = tid >> 6;
  const int lane = tid & 63;
  const int half = lane >> 5;
  const int l32  = lane & 31;

  // q fragments: lane holds dims l32*4..+3 for each of the 4 group heads
  float4 q[GRP];
#pragma unroll
  for (int g = 0; g < GRP; ++g)
    q[g] = *(const float4*)(qrot + ((size_t)(b * NH + kvh * GRP + g)) * HD + l32 * 4);

  const float4* kbase = (const float4*)(cache_k + ((size_t)(kvh * B + b)) * WIN * HD);
  const float4* vbase = (const float4*)(cache_v + ((size_t)(kvh * B + b)) * WIN * HD);

  float  l[GRP] = {0.f, 0.f, 0.f, 0.f};
  float4 acc[GRP] = {};

  const int s0 = chunk * SCHUNK;
  // wave's position for slot j in super-iter i: p = s0 + i*32 + wave*8 + 2j + half
  // load address (float4 idx): (p)*32 + l32 ; slot stride = 2 rows = 64

#define SUPER_COMPUTE(KARR, VARR, PBASE)                                     \
  {                                                                          \
    _Pragma("unroll")                                                        \
    for (int j = 0; j < 4; ++j) {                                            \
      const int p = (PBASE) + 2 * j + half;                                  \
      float s[GRP];                                                          \
      _Pragma("unroll")                                                      \
      for (int g = 0; g < GRP; ++g)                                          \
        s[g] = q[g].x*KARR[j].x + q[g].y*KARR[j].y                           \
             + q[g].z*KARR[j].z + q[g].w*KARR[j].w;                          \
      _Pragma("unroll")                                                      \
      for (int off = 1; off <= 16; off <<= 1) {                              \
        _Pragma("unroll")                                                    \
        for (int g = 0; g < GRP; ++g) s[g] += __shfl_xor(s[g], off);         \
      }                                                                      \
      const bool ok = p < slice;                                             \
      _Pragma("unroll")                                                      \
      for (int g = 0; g < GRP; ++g) {                                        \
        float w = ok ? fast_exp2(s[g]) : 0.f;                                \
        l[g] += w;                                                           \
        acc[g].x += w * VARR[j].x; acc[g].y += w * VARR[j].y;                \
        acc[g].z += w * VARR[j].z; acc[g].w += w * VARR[j].w;                \
      }                                                                      \
    }                                                                        \
  }

  {
    float4 k[4], v[4], kn[4], vn[4];
    size_t base = (size_t)(s0 + wave * 8 + half) * 32 + l32;
#pragma unroll
    for (int j = 0; j < 4; ++j) k[j] = kbase[base + (size_t)j * 64];
#pragma unroll
    for (int j = 0; j < 4; ++j) v[j] = vbase[base + (size_t)j * 64];

    int pbase = s0 + wave * 8;
#pragma unroll 1
    for (int i = 1; i < NSUP; ++i) {
      base += 32 * 32;   // +32 rows
      // prefetch next super-iteration (4KB K burst, 4KB V burst)
#pragma unroll
      for (int j = 0; j < 4; ++j) kn[j] = kbase[base + (size_t)j * 64];
#pragma unroll
      for (int j = 0; j < 4; ++j) vn[j] = vbase[base + (size_t)j * 64];

      SUPER_COMPUTE(k, v, pbase);

#pragma unroll
      for (int j = 0; j < 4; ++j) { k[j] = kn[j]; v[j] = vn[j]; }
      pbase += 32;
    }
    SUPER_COMPUTE(k, v, pbase);
  }

  // Correct the new-token position: subtract stale contribution, add new one.
  // p = s0 + i*32 + wave*8 + 2j + half == cur  ->  wave = (cur>>3)&3, half = cur&1.
  if (chunk == (cur >> 8) && wave == ((cur >> 3) & 3) && half == (cur & 1)) {
    const float4 kst = kbase[(size_t)cur * 32 + l32];
    const float4 vst = vbase[(size_t)cur * 32 + l32];
    const float4 knew = *(const float4*)(krot + ((size_t)(b * NKV + kvh)) * HD + l32 * 4);
    const float4 vnew = *(const float4*)(xqkv + (size_t)b * NQKV + (NH + NKV + kvh) * HD + l32 * 4);
    float sst[GRP], snw[GRP];
#pragma unroll
    for (int g = 0; g < GRP; ++g) {
      sst[g] = q[g].x*kst.x + q[g].y*kst.y + q[g].z*kst.z + q[g].w*kst.w;
      snw[g] = q[g].x*knew.x + q[g].y*knew.y + q[g].z*knew.z + q[g].w*knew.w;
    }
#pragma unroll
    for (int off = 1; off <= 16; off <<= 1) {
#pragma unroll
      for (int g = 0; g < GRP; ++g) {
        sst[g] += __shfl_xor(sst[g], off);
        snw[g] += __shfl_xor(snw[g], off);
      }
    }
#pragma unroll
    for (int g = 0; g < GRP; ++g) {
      float wst = fast_exp2(sst[g]);
      float wnw = fast_exp2(snw[g]);
      l[g] += wnw - wst;
      acc[g].x += wnw*vnew.x - wst*vst.x;
      acc[g].y += wnw*vnew.y - wst*vst.y;
      acc[g].z += wnw*vnew.z - wst*vst.z;
      acc[g].w += wnw*vnew.w - wst*vst.w;
    }
  }

  // combine the two halves of the wave (same heads, different positions)
#pragma unroll
  for (int g = 0; g < GRP; ++g) {
    l[g] += __shfl_xor(l[g], 32);
    acc[g].x += __shfl_xor(acc[g].x, 32);
    acc[g].y += __shfl_xor(acc[g].y, 32);
    acc[g].z += __shfl_xor(acc[g].z, 32);
    acc[g].w += __shfl_xor(acc[g].w, 32);
  }

  // combine the 4 waves via LDS
  __shared__ float red_l[4][GRP];
  __shared__ float red_o[4][GRP][HD];
  if (lane == 0) {
#pragma unroll
    for (int g = 0; g < GRP; ++g) red_l[wave][g] = l[g];
  }
  if (half == 0) {
#pragma unroll
    for (int g = 0; g < GRP; ++g)
      *(float4*)&red_o[wave][g][l32 * 4] = acc[g];
  }
  __syncthreads();

  const size_t pc = (size_t)pair * SPLIT + chunk;
  for (int idx = tid; idx < GRP * HD; idx += 256) {
    int g = idx >> 7, d = idx & 127;
    float o = red_o[0][g][d] + red_o[1][g][d] + red_o[2][g][d] + red_o[3][g][d];
    o_part[(pc * GRP + g) * HD + d] = o;
  }
  if (tid < GRP) {
    l_part[pc * GRP + tid] =
        red_l[0][tid] + red_l[1][tid] + red_l[2][tid] + red_l[3][tid];
  }
}

// ---------------------------------------------------------------------------
// Combine the SPLIT chunk partials -> attn_out[b][n*128 + d]
// ---------------------------------------------------------------------------
__global__ __launch_bounds__(128)
void attn_combine(const float* __restrict__ o_part, const float* __restrict__ l_part,
                  float* __restrict__ attn_out) {
  const int bid = blockIdx.x;   // b*32 + n
  const int b = bid >> 5, n = bid & 31;
  const int pair = b * NKV + (n >> 2);
  const int g = n & 3;
  const int d = threadIdx.x;

  float lsum = 0.f, osum = 0.f;
#pragma unroll
  for (int c = 0; c < SPLIT; ++c) {
    size_t pc = (size_t)pair * SPLIT + c;
    lsum += l_part[pc * GRP + g];
    osum += o_part[(pc * GRP + g) * HD + d];
  }
  attn_out[(size_t)b * DIM + n * HD + d] = osum / lsum;
}

// ---------------------------------------------------------------------------
extern "C" void kernel_launch(void* const* d_in, const int* in_sizes, int n_in,
                              void* d_out, int out_size, void* d_ws, size_t ws_size,
                              hipStream_t stream) {
  (void)in_sizes; (void)n_in; (void)out_size; (void)ws_size;

  const float* x    = (const float*)d_in[0];  // [1,1,32,4096]
  const float* wqkv = (const float*)d_in[1];  // [4096,6144]
  const float* wo   = (const float*)d_in[2];  // [4096,4096]
  const float* rot  = (const float*)d_in[3];  // [128,128]
  const float* ck   = (const float*)d_in[4];  // [8,32,4096,128]
  const float* cv   = (const float*)d_in[5];  // [8,32,4096,128]
  const int*   sp   = (const int*)d_in[6];    // scalar
  float* out = (float*)d_out;                 // [32,4096]

  float* ws       = (float*)d_ws;
  float* part     = ws;
  float* o_part   = ws;   // aliases part (lifetimes disjoint)
  float* xqkv     = part + (size_t)KS * B * NQKV;
  float* qrot     = xqkv + (size_t)B * NQKV;
  float* krot     = qrot + (size_t)B * NH * HD;
  float* l_part   = krot + (size_t)B * NKV * HD;
  float* attn_out = l_part + (size_t)B * NKV * SPLIT * GRP;

  // 1) xqkv = x @ wqkv  (split-K partials, then reduce)
  gemv32_partial<<<dim3(NQKV / 256, KS), 256, 0, stream>>>(x, wqkv, part, DIM, NQKV);
  reduce_partials<<<(B * NQKV) / 256, 256, 0, stream>>>(part, xqkv, B * NQKV);

  // 2) rotary on q (scaled; exp2 base folded in) and k
  rotary_kernel<<<dim3(B, NH + NKV), 128, 0, stream>>>(xqkv, rot, qrot, krot);

  // 3) flash-decode attention (phase-grouped 4KB bursts, unique addresses)
  attn_partial<<<dim3(B * NKV, SPLIT), 256, 0, stream>>>(ck, cv, qrot, krot, xqkv,
                                                         sp, o_part, l_part);
  attn_combine<<<B * NH, 128, 0, stream>>>(o_part, l_part, attn_out);

  // 4) dense = attn_out @ wo
  gemv32_partial<<<dim3(DIM / 256, KS), 256, 0, stream>>>(attn_out, wo, part, DIM, DIM);
  reduce_partials<<<(B * DIM) / 256, 256, 0, stream>>>(part, out, B * DIM);
}

// Round 12
// 307.860 us; speedup vs baseline: 1.0194x; 1.0194x over previous
//
#include <hip/hip_runtime.h>
#include <math.h>

#define B 32
#define NH 32
#define NKV 8
#define GRP 4
#define HD 128
#define DIM 4096
#define NQKV 6144   // (NH + 2*NKV) * HD
#define WIN 4096
#define KS 32       // split-K chunks for the skinny GEMMs
#define SPLIT 16    // attention sequence chunks
#define SCHUNK (WIN / SPLIT)   // 256 positions per chunk
#define WITER (SCHUNK / 4)     // 64 iterations per wave (4 waves = 4 pos-slots)

__device__ __forceinline__ float fast_exp2(float x) {
#if __has_builtin(__builtin_amdgcn_exp2f)
  return __builtin_amdgcn_exp2f(x);
#else
  return exp2f(x);
#endif
}

// DPP-based add of a lane-permuted copy (VALU pipe, not LDS pipe).
template <int CTRL>
__device__ __forceinline__ float dpp_add(float x) {
  int s = __builtin_amdgcn_update_dpp(0, __float_as_int(x), CTRL, 0xF, 0xF, true);
  return x + __int_as_float(s);
}

// Sum across each 32-lane half: 4 VALU-DPP levels + ONE ds_swizzle (xor16).
// Replaces 5 ds_bpermute ops -> 5x less traffic on the per-CU LDS pipe.
__device__ __forceinline__ float half32_sum(float t) {
  t = dpp_add<0xB1>(t);    // quad_perm(1,0,3,2)  : xor 1
  t = dpp_add<0x4E>(t);    // quad_perm(2,3,0,1)  : xor 2
  t = dpp_add<0x141>(t);   // row_half_mirror     : combines 4-groups
  t = dpp_add<0x140>(t);   // row_mirror          : combines 8-groups
  int s = __builtin_amdgcn_ds_swizzle(__float_as_int(t), 0x401F);  // xor 16
  return t + __int_as_float(s);
}

// ---------------------------------------------------------------------------
// Skinny GEMM (R4 known-good): part[kc][b][f] = sum_{k in kc} X[b][k]*W[k][f]
// Grid (N/256, KS), block 256. LDS-staged X, broadcast float4 reads.
// ---------------------------------------------------------------------------
__global__ __launch_bounds__(256)
void gemv32_partial(const float* __restrict__ X, const float* __restrict__ W,
                    float* __restrict__ part, int K, int N) {
  const int f  = blockIdx.x * 256 + threadIdx.x;
  const int kc = blockIdx.y;
  const int kchunk = K / KS;
  const int k0 = kc * kchunk;

  __shared__ float xs[128][36];

  float acc[B];
#pragma unroll
  for (int b = 0; b < B; ++b) acc[b] = 0.f;

  for (int kb = 0; kb < kchunk; kb += 128) {
    __syncthreads();
    for (int idx = threadIdx.x; idx < B * 128; idx += 256) {
      int bb = idx >> 7;
      int kk = idx & 127;
      xs[kk][bb] = X[(size_t)bb * K + (k0 + kb + kk)];
    }
    __syncthreads();

    const float* wp = W + (size_t)(k0 + kb) * N + f;
#pragma unroll 4
    for (int kk = 0; kk < 128; ++kk) {
      float w = wp[(size_t)kk * N];
      const float4* xr = (const float4*)&xs[kk][0];
#pragma unroll
      for (int b4 = 0; b4 < 8; ++b4) {
        float4 xv = xr[b4];
        acc[b4 * 4 + 0] += xv.x * w;
        acc[b4 * 4 + 1] += xv.y * w;
        acc[b4 * 4 + 2] += xv.z * w;
        acc[b4 * 4 + 3] += xv.w * w;
      }
    }
  }

  float* pp = part + (size_t)kc * B * N + f;
#pragma unroll
  for (int b = 0; b < B; ++b) pp[(size_t)b * N] = acc[b];
}

// ---------------------------------------------------------------------------
// Reduce split-K partials: out[idx] = sum_kc part[kc][idx]
// ---------------------------------------------------------------------------
__global__ __launch_bounds__(256)
void reduce_partials(const float* __restrict__ part, float* __restrict__ out,
                     int total) {
  int idx = blockIdx.x * 256 + threadIdx.x;
  if (idx >= total) return;
  float s = 0.f;
#pragma unroll
  for (int kc = 0; kc < KS; ++kc) s += part[(size_t)kc * total + idx];
  out[idx] = s;
}

// ---------------------------------------------------------------------------
// Rotary: per (b, head) vector v (128), out[e] = sum_d v[d] * rot[d][e]
// q heads scaled by rsqrt(128)*log2(e) (fixed-base-2 softmax); k unscaled.
// ---------------------------------------------------------------------------
__global__ __launch_bounds__(128)
void rotary_kernel(const float* __restrict__ xqkv, const float* __restrict__ rot,
                   float* __restrict__ qrot, float* __restrict__ krot) {
  const int b = blockIdx.x;
  const int h = blockIdx.y;   // 0..39
  const int e = threadIdx.x;  // 0..127

  __shared__ float vec[HD];
  vec[e] = xqkv[(size_t)b * NQKV + h * HD + e];
  __syncthreads();

  float s = 0.f;
#pragma unroll 8
  for (int d = 0; d < HD; ++d) s += vec[d] * rot[d * HD + e];

  const float QSCALE = 0.08838834764831845f * 1.4426950408889634f;
  if (h < NH) {
    qrot[((size_t)b * NH + h) * HD + e] = s * QSCALE;
  } else {
    krot[((size_t)b * NKV + (h - NH)) * HD + e] = s;
  }
}

// ---------------------------------------------------------------------------
// Flash-decode attention partial (fixed-base softmax). R8 structure:
// wave = position slot (p = s0 + i*4 + wave), half 0 -> heads 0-1,
// half 1 -> heads 2-3; both halves read the same K/V row. Score reduce now
// via DPP (VALU pipe) + one ds_swizzle, cutting per-CU LDS-pipe traffic 5x.
// Stale-cache loop + one-shot new-token correction.
// Grid (B*NKV, SPLIT), block 256.
// ---------------------------------------------------------------------------
__global__ __launch_bounds__(256)
void attn_partial(const float* __restrict__ cache_k, const float* __restrict__ cache_v,
                  const float* __restrict__ qrot, const float* __restrict__ krot,
                  const float* __restrict__ xqkv, const int* __restrict__ start_pos,
                  float* __restrict__ o_part, float* __restrict__ l_part) {
  const int pair = blockIdx.x;            // b * NKV + kvh
  const int b    = pair >> 3;
  const int kvh  = pair & 7;
  const int chunk = blockIdx.y;

  const int sp    = start_pos[0];
  const int cur   = sp & (WIN - 1);
  const int slice = (sp + 1 < WIN) ? (sp + 1) : WIN;

  const int tid  = threadIdx.x;
  const int wave = tid >> 6;
  const int lane = tid & 63;
  const int half = lane >> 5;
  const int l32  = lane & 31;

  // my two heads: half*2, half*2+1
  const float* qp = qrot + ((size_t)(b * NH + kvh * GRP + half * 2)) * HD + l32 * 4;
  const float4 q0 = *(const float4*)qp;
  const float4 q1 = *(const float4*)(qp + HD);

  const float4* kbase = (const float4*)(cache_k + ((size_t)(kvh * B + b)) * WIN * HD);
  const float4* vbase = (const float4*)(cache_v + ((size_t)(kvh * B + b)) * WIN * HD);

  float  l0 = 0.f, l1 = 0.f;
  float4 acc0 = {}, acc1 = {};

  const int s0 = chunk * SCHUNK;
  int rem = slice - s0 - wave;
  int n_i = rem <= 0 ? 0 : ((rem + 3) >> 2);
  if (n_i > WITER) n_i = WITER;

#define ATTN_BODY(K4, V4)                                                  \
  {                                                                        \
    float t0 = q0.x*K4.x + q0.y*K4.y + q0.z*K4.z + q0.w*K4.w;              \
    float t1 = q1.x*K4.x + q1.y*K4.y + q1.z*K4.z + q1.w*K4.w;              \
    t0 = half32_sum(t0);                                                   \
    t1 = half32_sum(t1);                                                   \
    float w0 = fast_exp2(t0), w1 = fast_exp2(t1);                          \
    l0 += w0; l1 += w1;                                                    \
    acc0.x += w0*V4.x; acc0.y += w0*V4.y; acc0.z += w0*V4.z; acc0.w += w0*V4.w; \
    acc1.x += w1*V4.x; acc1.y += w1*V4.y; acc1.z += w1*V4.z; acc1.w += w1*V4.w; \
  }

  if (n_i > 0) {
    size_t rb = ((size_t)(s0 + wave)) * 32 + l32;
    float4 k4 = kbase[rb];
    float4 v4 = vbase[rb];
#pragma unroll 2
    for (int i = 1; i < n_i; ++i) {
      rb += 4 * 32;
      float4 kn = kbase[rb];
      float4 vn = vbase[rb];
      ATTN_BODY(k4, v4);
      k4 = kn; v4 = vn;
    }
    ATTN_BODY(k4, v4);
  }

  // Correct the new-token position: subtract stale contribution, add new one.
  // Owning wave: p = s0 + i*4 + wave == cur  ->  chunk and wave match.
  if (chunk == (cur >> 8) && wave == (cur & 3)) {
    const float4 kst = kbase[(size_t)cur * 32 + l32];
    const float4 vst = vbase[(size_t)cur * 32 + l32];
    const float4 knew = *(const float4*)(krot + ((size_t)(b * NKV + kvh)) * HD + l32 * 4);
    const float4 vnew = *(const float4*)(xqkv + (size_t)b * NQKV + (NH + NKV + kvh) * HD + l32 * 4);

    float s0st = half32_sum(q0.x*kst.x + q0.y*kst.y + q0.z*kst.z + q0.w*kst.w);
    float s1st = half32_sum(q1.x*kst.x + q1.y*kst.y + q1.z*kst.z + q1.w*kst.w);
    float s0nw = half32_sum(q0.x*knew.x + q0.y*knew.y + q0.z*knew.z + q0.w*knew.w);
    float s1nw = half32_sum(q1.x*knew.x + q1.y*knew.y + q1.z*knew.z + q1.w*knew.w);

    float w0st = fast_exp2(s0st), w1st = fast_exp2(s1st);
    float w0nw = fast_exp2(s0nw), w1nw = fast_exp2(s1nw);
    l0 += w0nw - w0st;
    l1 += w1nw - w1st;
    acc0.x += w0nw*vnew.x - w0st*vst.x;  acc0.y += w0nw*vnew.y - w0st*vst.y;
    acc0.z += w0nw*vnew.z - w0st*vst.z;  acc0.w += w0nw*vnew.w - w0st*vst.w;
    acc1.x += w1nw*vnew.x - w1st*vst.x;  acc1.y += w1nw*vnew.y - w1st*vst.y;
    acc1.z += w1nw*vnew.z - w1st*vst.z;  acc1.w += w1nw*vnew.w - w1st*vst.w;
  }

  // combine the 4 waves via LDS (halves hold different heads -> no xor-32)
  __shared__ float red_l[4][GRP];
  __shared__ float red_o[4][GRP][HD];
  {
    const int h0 = half * 2;
    *(float4*)&red_o[wave][h0 + 0][l32 * 4] = acc0;
    *(float4*)&red_o[wave][h0 + 1][l32 * 4] = acc1;
    if (l32 == 0) {
      red_l[wave][h0 + 0] = l0;
      red_l[wave][h0 + 1] = l1;
    }
  }
  __syncthreads();

  const size_t pc = (size_t)pair * SPLIT + chunk;
  for (int idx = tid; idx < GRP * HD; idx += 256) {
    int g = idx >> 7, d = idx & 127;
    float o = red_o[0][g][d] + red_o[1][g][d] + red_o[2][g][d] + red_o[3][g][d];
    o_part[(pc * GRP + g) * HD + d] = o;
  }
  if (tid < GRP) {
    l_part[pc * GRP + tid] =
        red_l[0][tid] + red_l[1][tid] + red_l[2][tid] + red_l[3][tid];
  }
}

// ---------------------------------------------------------------------------
// Combine the SPLIT chunk partials -> attn_out[b][n*128 + d]
// ---------------------------------------------------------------------------
__global__ __launch_bounds__(128)
void attn_combine(const float* __restrict__ o_part, const float* __restrict__ l_part,
                  float* __restrict__ attn_out) {
  const int bid = blockIdx.x;   // b*32 + n
  const int b = bid >> 5, n = bid & 31;
  const int pair = b * NKV + (n >> 2);
  const int g = n & 3;
  const int d = threadIdx.x;

  float lsum = 0.f, osum = 0.f;
#pragma unroll
  for (int c = 0; c < SPLIT; ++c) {
    size_t pc = (size_t)pair * SPLIT + c;
    lsum += l_part[pc * GRP + g];
    osum += o_part[(pc * GRP + g) * HD + d];
  }
  attn_out[(size_t)b * DIM + n * HD + d] = osum / lsum;
}

// ---------------------------------------------------------------------------
extern "C" void kernel_launch(void* const* d_in, const int* in_sizes, int n_in,
                              void* d_out, int out_size, void* d_ws, size_t ws_size,
                              hipStream_t stream) {
  (void)in_sizes; (void)n_in; (void)out_size; (void)ws_size;

  const float* x    = (const float*)d_in[0];  // [1,1,32,4096]
  const float* wqkv = (const float*)d_in[1];  // [4096,6144]
  const float* wo   = (const float*)d_in[2];  // [4096,4096]
  const float* rot  = (const float*)d_in[3];  // [128,128]
  const float* ck   = (const float*)d_in[4];  // [8,32,4096,128]
  const float* cv   = (const float*)d_in[5];  // [8,32,4096,128]
  const int*   sp   = (const int*)d_in[6];    // scalar
  float* out = (float*)d_out;                 // [32,4096]

  float* ws       = (float*)d_ws;
  float* part     = ws;
  float* o_part   = ws;   // aliases part (lifetimes disjoint)
  float* xqkv     = part + (size_t)KS * B * NQKV;
  float* qrot     = xqkv + (size_t)B * NQKV;
  float* krot     = qrot + (size_t)B * NH * HD;
  float* l_part   = krot + (size_t)B * NKV * HD;
  float* attn_out = l_part + (size_t)B * NKV * SPLIT * GRP;

  // 1) xqkv = x @ wqkv  (split-K partials, then reduce)
  gemv32_partial<<<dim3(NQKV / 256, KS), 256, 0, stream>>>(x, wqkv, part, DIM, NQKV);
  reduce_partials<<<(B * NQKV) / 256, 256, 0, stream>>>(part, xqkv, B * NQKV);

  // 2) rotary on q (scaled; exp2 base folded in) and k
  rotary_kernel<<<dim3(B, NH + NKV), 128, 0, stream>>>(xqkv, rot, qrot, krot);

  // 3) flash-decode attention (DPP reduce: LDS-pipe traffic cut 5x)
  attn_partial<<<dim3(B * NKV, SPLIT), 256, 0, stream>>>(ck, cv, qrot, krot, xqkv,
                                                         sp, o_part, l_part);
  attn_combine<<<B * NH, 128, 0, stream>>>(o_part, l_part, attn_out);

  // 4) dense = attn_out @ wo
  gemv32_partial<<<dim3(DIM / 256, KS), 256, 0, stream>>>(attn_out, wo, part, DIM, DIM);
  reduce_partials<<<(B * DIM) / 256, 256, 0, stream>>>(part, out, B * DIM);
}

// Round 13
// 270.066 us; speedup vs baseline: 1.1620x; 1.1399x over previous
//
#include <hip/hip_runtime.h>
#include <math.h>

#define B 32
#define NH 32
#define NKV 8
#define GRP 4
#define HD 128
#define DIM 4096
#define NQKV 6144   // (NH + 2*NKV) * HD
#define WIN 4096
#define KS 32       // split-K chunks for the skinny GEMMs
#define SPLIT 16    // attention sequence chunks
#define SCHUNK (WIN / SPLIT)   // 256 positions per chunk
#define WITER (SCHUNK / 4)     // 64 iterations per wave (4 waves = 4 pos-slots)

typedef float f32x4 __attribute__((ext_vector_type(4)));

__device__ __forceinline__ float fast_exp2(float x) {
#if __has_builtin(__builtin_amdgcn_exp2f)
  return __builtin_amdgcn_exp2f(x);
#else
  return exp2f(x);
#endif
}

// Streaming (non-temporal) 16B load: K/V rows are touched exactly once per
// dispatch, so bypass cache allocation on the read path.
__device__ __forceinline__ f32x4 nt_load4(const float* p) {
  return __builtin_nontemporal_load((const f32x4*)p);
}

// ---------------------------------------------------------------------------
// Skinny GEMM (R4 known-good): part[kc][b][f] = sum_{k in kc} X[b][k]*W[k][f]
// Grid (N/256, KS), block 256. LDS-staged X, broadcast float4 reads.
// ---------------------------------------------------------------------------
__global__ __launch_bounds__(256)
void gemv32_partial(const float* __restrict__ X, const float* __restrict__ W,
                    float* __restrict__ part, int K, int N) {
  const int f  = blockIdx.x * 256 + threadIdx.x;
  const int kc = blockIdx.y;
  const int kchunk = K / KS;
  const int k0 = kc * kchunk;

  __shared__ float xs[128][36];

  float acc[B];
#pragma unroll
  for (int b = 0; b < B; ++b) acc[b] = 0.f;

  for (int kb = 0; kb < kchunk; kb += 128) {
    __syncthreads();
    for (int idx = threadIdx.x; idx < B * 128; idx += 256) {
      int bb = idx >> 7;
      int kk = idx & 127;
      xs[kk][bb] = X[(size_t)bb * K + (k0 + kb + kk)];
    }
    __syncthreads();

    const float* wp = W + (size_t)(k0 + kb) * N + f;
#pragma unroll 4
    for (int kk = 0; kk < 128; ++kk) {
      float w = wp[(size_t)kk * N];
      const float4* xr = (const float4*)&xs[kk][0];
#pragma unroll
      for (int b4 = 0; b4 < 8; ++b4) {
        float4 xv = xr[b4];
        acc[b4 * 4 + 0] += xv.x * w;
        acc[b4 * 4 + 1] += xv.y * w;
        acc[b4 * 4 + 2] += xv.z * w;
        acc[b4 * 4 + 3] += xv.w * w;
      }
    }
  }

  float* pp = part + (size_t)kc * B * N + f;
#pragma unroll
  for (int b = 0; b < B; ++b) pp[(size_t)b * N] = acc[b];
}

// ---------------------------------------------------------------------------
// Reduce split-K partials: out[idx] = sum_kc part[kc][idx]
// ---------------------------------------------------------------------------
__global__ __launch_bounds__(256)
void reduce_partials(const float* __restrict__ part, float* __restrict__ out,
                     int total) {
  int idx = blockIdx.x * 256 + threadIdx.x;
  if (idx >= total) return;
  float s = 0.f;
#pragma unroll
  for (int kc = 0; kc < KS; ++kc) s += part[(size_t)kc * total + idx];
  out[idx] = s;
}

// ---------------------------------------------------------------------------
// Rotary: per (b, head) vector v (128), out[e] = sum_d v[d] * rot[d][e]
// q heads scaled by rsqrt(128)*log2(e) (fixed-base-2 softmax); k unscaled.
// ---------------------------------------------------------------------------
__global__ __launch_bounds__(128)
void rotary_kernel(const float* __restrict__ xqkv, const float* __restrict__ rot,
                   float* __restrict__ qrot, float* __restrict__ krot) {
  const int b = blockIdx.x;
  const int h = blockIdx.y;   // 0..39
  const int e = threadIdx.x;  // 0..127

  __shared__ float vec[HD];
  vec[e] = xqkv[(size_t)b * NQKV + h * HD + e];
  __syncthreads();

  float s = 0.f;
#pragma unroll 8
  for (int d = 0; d < HD; ++d) s += vec[d] * rot[d * HD + e];

  const float QSCALE = 0.08838834764831845f * 1.4426950408889634f;
  if (h < NH) {
    qrot[((size_t)b * NH + h) * HD + e] = s * QSCALE;
  } else {
    krot[((size_t)b * NKV + (h - NH)) * HD + e] = s;
  }
}

// ---------------------------------------------------------------------------
// Flash-decode attention partial (fixed-base softmax). R8 structure:
// wave = position slot (p = s0 + i*4 + wave), half 0 -> heads 0-1,
// half 1 -> heads 2-3; both halves read the same K/V row. K/V main-loop
// loads are NON-TEMPORAL (streamed, no cache allocation) — each row is
// touched exactly once per dispatch. Stale-cache loop + one-shot new-token
// correction. Grid (B*NKV, SPLIT), block 256.
// ---------------------------------------------------------------------------
__global__ __launch_bounds__(256)
void attn_partial(const float* __restrict__ cache_k, const float* __restrict__ cache_v,
                  const float* __restrict__ qrot, const float* __restrict__ krot,
                  const float* __restrict__ xqkv, const int* __restrict__ start_pos,
                  float* __restrict__ o_part, float* __restrict__ l_part) {
  const int pair = blockIdx.x;            // b * NKV + kvh
  const int b    = pair >> 3;
  const int kvh  = pair & 7;
  const int chunk = blockIdx.y;

  const int sp    = start_pos[0];
  const int cur   = sp & (WIN - 1);
  const int slice = (sp + 1 < WIN) ? (sp + 1) : WIN;

  const int tid  = threadIdx.x;
  const int wave = tid >> 6;
  const int lane = tid & 63;
  const int half = lane >> 5;
  const int l32  = lane & 31;

  // my two heads: half*2, half*2+1
  const float* qp = qrot + ((size_t)(b * NH + kvh * GRP + half * 2)) * HD + l32 * 4;
  const float4 q0 = *(const float4*)qp;
  const float4 q1 = *(const float4*)(qp + HD);

  const float* kbase = cache_k + ((size_t)(kvh * B + b)) * WIN * HD;
  const float* vbase = cache_v + ((size_t)(kvh * B + b)) * WIN * HD;

  float  l0 = 0.f, l1 = 0.f;
  float4 acc0 = {}, acc1 = {};

  const int s0 = chunk * SCHUNK;
  int rem = slice - s0 - wave;
  int n_i = rem <= 0 ? 0 : ((rem + 3) >> 2);
  if (n_i > WITER) n_i = WITER;

#define ATTN_BODY(K4, V4)                                                  \
  {                                                                        \
    float t0 = q0.x*K4.x + q0.y*K4.y + q0.z*K4.z + q0.w*K4.w;              \
    float t1 = q1.x*K4.x + q1.y*K4.y + q1.z*K4.z + q1.w*K4.w;              \
    t0 += __shfl_xor(t0, 1);  t1 += __shfl_xor(t1, 1);                     \
    t0 += __shfl_xor(t0, 2);  t1 += __shfl_xor(t1, 2);                     \
    t0 += __shfl_xor(t0, 4);  t1 += __shfl_xor(t1, 4);                     \
    t0 += __shfl_xor(t0, 8);  t1 += __shfl_xor(t1, 8);                     \
    t0 += __shfl_xor(t0, 16); t1 += __shfl_xor(t1, 16);                    \
    float w0 = fast_exp2(t0), w1 = fast_exp2(t1);                          \
    l0 += w0; l1 += w1;                                                    \
    acc0.x += w0*V4.x; acc0.y += w0*V4.y; acc0.z += w0*V4.z; acc0.w += w0*V4.w; \
    acc1.x += w1*V4.x; acc1.y += w1*V4.y; acc1.z += w1*V4.z; acc1.w += w1*V4.w; \
  }

  if (n_i > 0) {
    size_t off = ((size_t)(s0 + wave) * 32 + l32) * 4;   // float offset
    f32x4 k4 = nt_load4(kbase + off);
    f32x4 v4 = nt_load4(vbase + off);
#pragma unroll 2
    for (int i = 1; i < n_i; ++i) {
      off += 4 * 128;
      f32x4 kn = nt_load4(kbase + off);
      f32x4 vn = nt_load4(vbase + off);
      ATTN_BODY(k4, v4);
      k4 = kn; v4 = vn;
    }
    ATTN_BODY(k4, v4);
  }

  // Correct the new-token position: subtract stale contribution, add new one.
  // Owning wave: p = s0 + i*4 + wave == cur  ->  chunk and wave match.
  if (chunk == (cur >> 8) && wave == (cur & 3)) {
    const float4 kst = *(const float4*)(kbase + (size_t)cur * HD + l32 * 4);
    const float4 vst = *(const float4*)(vbase + (size_t)cur * HD + l32 * 4);
    const float4 knew = *(const float4*)(krot + ((size_t)(b * NKV + kvh)) * HD + l32 * 4);
    const float4 vnew = *(const float4*)(xqkv + (size_t)b * NQKV + (NH + NKV + kvh) * HD + l32 * 4);

    float s0st = q0.x*kst.x + q0.y*kst.y + q0.z*kst.z + q0.w*kst.w;
    float s1st = q1.x*kst.x + q1.y*kst.y + q1.z*kst.z + q1.w*kst.w;
    float s0nw = q0.x*knew.x + q0.y*knew.y + q0.z*knew.z + q0.w*knew.w;
    float s1nw = q1.x*knew.x + q1.y*knew.y + q1.z*knew.z + q1.w*knew.w;
#pragma unroll
    for (int off = 1; off <= 16; off <<= 1) {
      s0st += __shfl_xor(s0st, off);
      s1st += __shfl_xor(s1st, off);
      s0nw += __shfl_xor(s0nw, off);
      s1nw += __shfl_xor(s1nw, off);
    }
    float w0st = fast_exp2(s0st), w1st = fast_exp2(s1st);
    float w0nw = fast_exp2(s0nw), w1nw = fast_exp2(s1nw);
    l0 += w0nw - w0st;
    l1 += w1nw - w1st;
    acc0.x += w0nw*vnew.x - w0st*vst.x;  acc0.y += w0nw*vnew.y - w0st*vst.y;
    acc0.z += w0nw*vnew.z - w0st*vst.z;  acc0.w += w0nw*vnew.w - w0st*vst.w;
    acc1.x += w1nw*vnew.x - w1st*vst.x;  acc1.y += w1nw*vnew.y - w1st*vst.y;
    acc1.z += w1nw*vnew.z - w1st*vst.z;  acc1.w += w1nw*vnew.w - w1st*vst.w;
  }

  // combine the 4 waves via LDS (halves hold different heads -> no xor-32)
  __shared__ float red_l[4][GRP];
  __shared__ float red_o[4][GRP][HD];
  {
    const int h0 = half * 2;
    *(float4*)&red_o[wave][h0 + 0][l32 * 4] = acc0;
    *(float4*)&red_o[wave][h0 + 1][l32 * 4] = acc1;
    if (l32 == 0) {
      red_l[wave][h0 + 0] = l0;
      red_l[wave][h0 + 1] = l1;
    }
  }
  __syncthreads();

  const size_t pc = (size_t)pair * SPLIT + chunk;
  for (int idx = tid; idx < GRP * HD; idx += 256) {
    int g = idx >> 7, d = idx & 127;
    float o = red_o[0][g][d] + red_o[1][g][d] + red_o[2][g][d] + red_o[3][g][d];
    o_part[(pc * GRP + g) * HD + d] = o;
  }
  if (tid < GRP) {
    l_part[pc * GRP + tid] =
        red_l[0][tid] + red_l[1][tid] + red_l[2][tid] + red_l[3][tid];
  }
}

// ---------------------------------------------------------------------------
// Combine the SPLIT chunk partials -> attn_out[b][n*128 + d]
// ---------------------------------------------------------------------------
__global__ __launch_bounds__(128)
void attn_combine(const float* __restrict__ o_part, const float* __restrict__ l_part,
                  float* __restrict__ attn_out) {
  const int bid = blockIdx.x;   // b*32 + n
  const int b = bid >> 5, n = bid & 31;
  const int pair = b * NKV + (n >> 2);
  const int g = n & 3;
  const int d = threadIdx.x;

  float lsum = 0.f, osum = 0.f;
#pragma unroll
  for (int c = 0; c < SPLIT; ++c) {
    size_t pc = (size_t)pair * SPLIT + c;
    lsum += l_part[pc * GRP + g];
    osum += o_part[(pc * GRP + g) * HD + d];
  }
  attn_out[(size_t)b * DIM + n * HD + d] = osum / lsum;
}

// ---------------------------------------------------------------------------
extern "C" void kernel_launch(void* const* d_in, const int* in_sizes, int n_in,
                              void* d_out, int out_size, void* d_ws, size_t ws_size,
                              hipStream_t stream) {
  (void)in_sizes; (void)n_in; (void)out_size; (void)ws_size;

  const float* x    = (const float*)d_in[0];  // [1,1,32,4096]
  const float* wqkv = (const float*)d_in[1];  // [4096,6144]
  const float* wo   = (const float*)d_in[2];  // [4096,4096]
  const float* rot  = (const float*)d_in[3];  // [128,128]
  const float* ck   = (const float*)d_in[4];  // [8,32,4096,128]
  const float* cv   = (const float*)d_in[5];  // [8,32,4096,128]
  const int*   sp   = (const int*)d_in[6];    // scalar
  float* out = (float*)d_out;                 // [32,4096]

  float* ws       = (float*)d_ws;
  float* part     = ws;
  float* o_part   = ws;   // aliases part (lifetimes disjoint)
  float* xqkv     = part + (size_t)KS * B * NQKV;
  float* qrot     = xqkv + (size_t)B * NQKV;
  float* krot     = qrot + (size_t)B * NH * HD;
  float* l_part   = krot + (size_t)B * NKV * HD;
  float* attn_out = l_part + (size_t)B * NKV * SPLIT * GRP;

  // 1) xqkv = x @ wqkv  (split-K partials, then reduce)
  gemv32_partial<<<dim3(NQKV / 256, KS), 256, 0, stream>>>(x, wqkv, part, DIM, NQKV);
  reduce_partials<<<(B * NQKV) / 256, 256, 0, stream>>>(part, xqkv, B * NQKV);

  // 2) rotary on q (scaled; exp2 base folded in) and k
  rotary_kernel<<<dim3(B, NH + NKV), 128, 0, stream>>>(xqkv, rot, qrot, krot);

  // 3) flash-decode attention (non-temporal streaming K/V reads)
  attn_partial<<<dim3(B * NKV, SPLIT), 256, 0, stream>>>(ck, cv, qrot, krot, xqkv,
                                                         sp, o_part, l_part);
  attn_combine<<<B * NH, 128, 0, stream>>>(o_part, l_part, attn_out);

  // 4) dense = attn_out @ wo
  gemv32_partial<<<dim3(DIM / 256, KS), 256, 0, stream>>>(attn_out, wo, part, DIM, DIM);
  reduce_partials<<<(B * DIM) / 256, 256, 0, stream>>>(part, out, B * DIM);
}

// Round 14
// 267.587 us; speedup vs baseline: 1.1728x; 1.0093x over previous
//
#include <hip/hip_runtime.h>
#include <math.h>

#define B 32
#define NH 32
#define NKV 8
#define GRP 4
#define HD 128
#define DIM 4096
#define NQKV 6144   // (NH + 2*NKV) * HD
#define WIN 4096
#define KS 32       // split-K chunks for the skinny GEMMs
#define SPLIT 16    // attention sequence chunks
#define SCHUNK (WIN / SPLIT)   // 256 positions per chunk
#define WITER (SCHUNK / 4)     // 64 iterations per wave (4 waves = 4 pos-slots)

typedef float f32x4 __attribute__((ext_vector_type(4)));

__device__ __forceinline__ float fast_exp2(float x) {
#if __has_builtin(__builtin_amdgcn_exp2f)
  return __builtin_amdgcn_exp2f(x);
#else
  return exp2f(x);
#endif
}

// Streaming (non-temporal) loads: data touched exactly once per dispatch
// bypasses cache allocation on the read path (confirmed +33us on K/V, R13).
__device__ __forceinline__ f32x4 nt_load4(const float* p) {
  return __builtin_nontemporal_load((const f32x4*)p);
}
__device__ __forceinline__ float nt_load1(const float* p) {
  return __builtin_nontemporal_load(p);
}

// ---------------------------------------------------------------------------
// Skinny GEMM: part[kc][b][f] = sum_{k in kc} X[b][k]*W[k][f]
// Grid (N/256, KS), block 256. LDS-staged X, broadcast float4 reads.
// W is streamed with non-temporal loads (read exactly once per dispatch).
// ---------------------------------------------------------------------------
__global__ __launch_bounds__(256)
void gemv32_partial(const float* __restrict__ X, const float* __restrict__ W,
                    float* __restrict__ part, int K, int N) {
  const int f  = blockIdx.x * 256 + threadIdx.x;
  const int kc = blockIdx.y;
  const int kchunk = K / KS;
  const int k0 = kc * kchunk;

  __shared__ float xs[128][36];

  float acc[B];
#pragma unroll
  for (int b = 0; b < B; ++b) acc[b] = 0.f;

  for (int kb = 0; kb < kchunk; kb += 128) {
    __syncthreads();
    for (int idx = threadIdx.x; idx < B * 128; idx += 256) {
      int bb = idx >> 7;
      int kk = idx & 127;
      xs[kk][bb] = X[(size_t)bb * K + (k0 + kb + kk)];
    }
    __syncthreads();

    const float* wp = W + (size_t)(k0 + kb) * N + f;
#pragma unroll 4
    for (int kk = 0; kk < 128; ++kk) {
      float w = nt_load1(wp + (size_t)kk * N);
      const float4* xr = (const float4*)&xs[kk][0];
#pragma unroll
      for (int b4 = 0; b4 < 8; ++b4) {
        float4 xv = xr[b4];
        acc[b4 * 4 + 0] += xv.x * w;
        acc[b4 * 4 + 1] += xv.y * w;
        acc[b4 * 4 + 2] += xv.z * w;
        acc[b4 * 4 + 3] += xv.w * w;
      }
    }
  }

  float* pp = part + (size_t)kc * B * N + f;
#pragma unroll
  for (int b = 0; b < B; ++b) pp[(size_t)b * N] = acc[b];
}

// ---------------------------------------------------------------------------
// Reduce split-K partials: out[idx] = sum_kc part[kc][idx]
// (partials are freshly written -> cache-resident; keep normal loads)
// ---------------------------------------------------------------------------
__global__ __launch_bounds__(256)
void reduce_partials(const float* __restrict__ part, float* __restrict__ out,
                     int total) {
  int idx = blockIdx.x * 256 + threadIdx.x;
  if (idx >= total) return;
  float s = 0.f;
#pragma unroll
  for (int kc = 0; kc < KS; ++kc) s += part[(size_t)kc * total + idx];
  out[idx] = s;
}

// ---------------------------------------------------------------------------
// Rotary: per (b, head) vector v (128), out[e] = sum_d v[d] * rot[d][e]
// q heads scaled by rsqrt(128)*log2(e) (fixed-base-2 softmax); k unscaled.
// ---------------------------------------------------------------------------
__global__ __launch_bounds__(128)
void rotary_kernel(const float* __restrict__ xqkv, const float* __restrict__ rot,
                   float* __restrict__ qrot, float* __restrict__ krot) {
  const int b = blockIdx.x;
  const int h = blockIdx.y;   // 0..39
  const int e = threadIdx.x;  // 0..127

  __shared__ float vec[HD];
  vec[e] = xqkv[(size_t)b * NQKV + h * HD + e];
  __syncthreads();

  float s = 0.f;
#pragma unroll 8
  for (int d = 0; d < HD; ++d) s += vec[d] * rot[d * HD + e];

  const float QSCALE = 0.08838834764831845f * 1.4426950408889634f;
  if (h < NH) {
    qrot[((size_t)b * NH + h) * HD + e] = s * QSCALE;
  } else {
    krot[((size_t)b * NKV + (h - NH)) * HD + e] = s;
  }
}

// ---------------------------------------------------------------------------
// Flash-decode attention partial (fixed-base softmax). R8 structure:
// wave = position slot (p = s0 + i*4 + wave), half 0 -> heads 0-1,
// half 1 -> heads 2-3; both halves read the same K/V row. K/V main-loop
// loads are NON-TEMPORAL (streamed, no cache allocation) — each row is
// touched exactly once per dispatch. Stale-cache loop + one-shot new-token
// correction. Grid (B*NKV, SPLIT), block 256.
// ---------------------------------------------------------------------------
__global__ __launch_bounds__(256)
void attn_partial(const float* __restrict__ cache_k, const float* __restrict__ cache_v,
                  const float* __restrict__ qrot, const float* __restrict__ krot,
                  const float* __restrict__ xqkv, const int* __restrict__ start_pos,
                  float* __restrict__ o_part, float* __restrict__ l_part) {
  const int pair = blockIdx.x;            // b * NKV + kvh
  const int b    = pair >> 3;
  const int kvh  = pair & 7;
  const int chunk = blockIdx.y;

  const int sp    = start_pos[0];
  const int cur   = sp & (WIN - 1);
  const int slice = (sp + 1 < WIN) ? (sp + 1) : WIN;

  const int tid  = threadIdx.x;
  const int wave = tid >> 6;
  const int lane = tid & 63;
  const int half = lane >> 5;
  const int l32  = lane & 31;

  // my two heads: half*2, half*2+1
  const float* qp = qrot + ((size_t)(b * NH + kvh * GRP + half * 2)) * HD + l32 * 4;
  const float4 q0 = *(const float4*)qp;
  const float4 q1 = *(const float4*)(qp + HD);

  const float* kbase = cache_k + ((size_t)(kvh * B + b)) * WIN * HD;
  const float* vbase = cache_v + ((size_t)(kvh * B + b)) * WIN * HD;

  float  l0 = 0.f, l1 = 0.f;
  float4 acc0 = {}, acc1 = {};

  const int s0 = chunk * SCHUNK;
  int rem = slice - s0 - wave;
  int n_i = rem <= 0 ? 0 : ((rem + 3) >> 2);
  if (n_i > WITER) n_i = WITER;

#define ATTN_BODY(K4, V4)                                                  \
  {                                                                        \
    float t0 = q0.x*K4.x + q0.y*K4.y + q0.z*K4.z + q0.w*K4.w;              \
    float t1 = q1.x*K4.x + q1.y*K4.y + q1.z*K4.z + q1.w*K4.w;              \
    t0 += __shfl_xor(t0, 1);  t1 += __shfl_xor(t1, 1);                     \
    t0 += __shfl_xor(t0, 2);  t1 += __shfl_xor(t1, 2);                     \
    t0 += __shfl_xor(t0, 4);  t1 += __shfl_xor(t1, 4);                     \
    t0 += __shfl_xor(t0, 8);  t1 += __shfl_xor(t1, 8);                     \
    t0 += __shfl_xor(t0, 16); t1 += __shfl_xor(t1, 16);                    \
    float w0 = fast_exp2(t0), w1 = fast_exp2(t1);                          \
    l0 += w0; l1 += w1;                                                    \
    acc0.x += w0*V4.x; acc0.y += w0*V4.y; acc0.z += w0*V4.z; acc0.w += w0*V4.w; \
    acc1.x += w1*V4.x; acc1.y += w1*V4.y; acc1.z += w1*V4.z; acc1.w += w1*V4.w; \
  }

  if (n_i > 0) {
    size_t off = ((size_t)(s0 + wave) * 32 + l32) * 4;   // float offset
    f32x4 k4 = nt_load4(kbase + off);
    f32x4 v4 = nt_load4(vbase + off);
#pragma unroll 2
    for (int i = 1; i < n_i; ++i) {
      off += 4 * 128;
      f32x4 kn = nt_load4(kbase + off);
      f32x4 vn = nt_load4(vbase + off);
      ATTN_BODY(k4, v4);
      k4 = kn; v4 = vn;
    }
    ATTN_BODY(k4, v4);
  }

  // Correct the new-token position: subtract stale contribution, add new one.
  // Owning wave: p = s0 + i*4 + wave == cur  ->  chunk and wave match.
  if (chunk == (cur >> 8) && wave == (cur & 3)) {
    const float4 kst = *(const float4*)(kbase + (size_t)cur * HD + l32 * 4);
    const float4 vst = *(const float4*)(vbase + (size_t)cur * HD + l32 * 4);
    const float4 knew = *(const float4*)(krot + ((size_t)(b * NKV + kvh)) * HD + l32 * 4);
    const float4 vnew = *(const float4*)(xqkv + (size_t)b * NQKV + (NH + NKV + kvh) * HD + l32 * 4);

    float s0st = q0.x*kst.x + q0.y*kst.y + q0.z*kst.z + q0.w*kst.w;
    float s1st = q1.x*kst.x + q1.y*kst.y + q1.z*kst.z + q1.w*kst.w;
    float s0nw = q0.x*knew.x + q0.y*knew.y + q0.z*knew.z + q0.w*knew.w;
    float s1nw = q1.x*knew.x + q1.y*knew.y + q1.z*knew.z + q1.w*knew.w;
#pragma unroll
    for (int off = 1; off <= 16; off <<= 1) {
      s0st += __shfl_xor(s0st, off);
      s1st += __shfl_xor(s1st, off);
      s0nw += __shfl_xor(s0nw, off);
      s1nw += __shfl_xor(s1nw, off);
    }
    float w0st = fast_exp2(s0st), w1st = fast_exp2(s1st);
    float w0nw = fast_exp2(s0nw), w1nw = fast_exp2(s1nw);
    l0 += w0nw - w0st;
    l1 += w1nw - w1st;
    acc0.x += w0nw*vnew.x - w0st*vst.x;  acc0.y += w0nw*vnew.y - w0st*vst.y;
    acc0.z += w0nw*vnew.z - w0st*vst.z;  acc0.w += w0nw*vnew.w - w0st*vst.w;
    acc1.x += w1nw*vnew.x - w1st*vst.x;  acc1.y += w1nw*vnew.y - w1st*vst.y;
    acc1.z += w1nw*vnew.z - w1st*vst.z;  acc1.w += w1nw*vnew.w - w1st*vst.w;
  }

  // combine the 4 waves via LDS (halves hold different heads -> no xor-32)
  __shared__ float red_l[4][GRP];
  __shared__ float red_o[4][GRP][HD];
  {
    const int h0 = half * 2;
    *(float4*)&red_o[wave][h0 + 0][l32 * 4] = acc0;
    *(float4*)&red_o[wave][h0 + 1][l32 * 4] = acc1;
    if (l32 == 0) {
      red_l[wave][h0 + 0] = l0;
      red_l[wave][h0 + 1] = l1;
    }
  }
  __syncthreads();

  const size_t pc = (size_t)pair * SPLIT + chunk;
  for (int idx = tid; idx < GRP * HD; idx += 256) {
    int g = idx >> 7, d = idx & 127;
    float o = red_o[0][g][d] + red_o[1][g][d] + red_o[2][g][d] + red_o[3][g][d];
    o_part[(pc * GRP + g) * HD + d] = o;
  }
  if (tid < GRP) {
    l_part[pc * GRP + tid] =
        red_l[0][tid] + red_l[1][tid] + red_l[2][tid] + red_l[3][tid];
  }
}

// ---------------------------------------------------------------------------
// Combine the SPLIT chunk partials -> attn_out[b][n*128 + d]
// ---------------------------------------------------------------------------
__global__ __launch_bounds__(128)
void attn_combine(const float* __restrict__ o_part, const float* __restrict__ l_part,
                  float* __restrict__ attn_out) {
  const int bid = blockIdx.x;   // b*32 + n
  const int b = bid >> 5, n = bid & 31;
  const int pair = b * NKV + (n >> 2);
  const int g = n & 3;
  const int d = threadIdx.x;

  float lsum = 0.f, osum = 0.f;
#pragma unroll
  for (int c = 0; c < SPLIT; ++c) {
    size_t pc = (size_t)pair * SPLIT + c;
    lsum += l_part[pc * GRP + g];
    osum += o_part[(pc * GRP + g) * HD + d];
  }
  attn_out[(size_t)b * DIM + n * HD + d] = osum / lsum;
}

// ---------------------------------------------------------------------------
extern "C" void kernel_launch(void* const* d_in, const int* in_sizes, int n_in,
                              void* d_out, int out_size, void* d_ws, size_t ws_size,
                              hipStream_t stream) {
  (void)in_sizes; (void)n_in; (void)out_size; (void)ws_size;

  const float* x    = (const float*)d_in[0];  // [1,1,32,4096]
  const float* wqkv = (const float*)d_in[1];  // [4096,6144]
  const float* wo   = (const float*)d_in[2];  // [4096,4096]
  const float* rot  = (const float*)d_in[3];  // [128,128]
  const float* ck   = (const float*)d_in[4];  // [8,32,4096,128]
  const float* cv   = (const float*)d_in[5];  // [8,32,4096,128]
  const int*   sp   = (const int*)d_in[6];    // scalar
  float* out = (float*)d_out;                 // [32,4096]

  float* ws       = (float*)d_ws;
  float* part     = ws;
  float* o_part   = ws;   // aliases part (lifetimes disjoint)
  float* xqkv     = part + (size_t)KS * B * NQKV;
  float* qrot     = xqkv + (size_t)B * NQKV;
  float* krot     = qrot + (size_t)B * NH * HD;
  float* l_part   = krot + (size_t)B * NKV * HD;
  float* attn_out = l_part + (size_t)B * NKV * SPLIT * GRP;

  // 1) xqkv = x @ wqkv  (split-K partials, then reduce)
  gemv32_partial<<<dim3(NQKV / 256, KS), 256, 0, stream>>>(x, wqkv, part, DIM, NQKV);
  reduce_partials<<<(B * NQKV) / 256, 256, 0, stream>>>(part, xqkv, B * NQKV);

  // 2) rotary on q (scaled; exp2 base folded in) and k
  rotary_kernel<<<dim3(B, NH + NKV), 128, 0, stream>>>(xqkv, rot, qrot, krot);

  // 3) flash-decode attention (non-temporal streaming K/V reads)
  attn_partial<<<dim3(B * NKV, SPLIT), 256, 0, stream>>>(ck, cv, qrot, krot, xqkv,
                                                         sp, o_part, l_part);
  attn_combine<<<B * NH, 128, 0, stream>>>(o_part, l_part, attn_out);

  // 4) dense = attn_out @ wo (weights streamed non-temporally)
  gemv32_partial<<<dim3(DIM / 256, KS), 256, 0, stream>>>(attn_out, wo, part, DIM, DIM);
  reduce_partials<<<(B * DIM) / 256, 256, 0, stream>>>(part, out, B * DIM);
}